// Round 1
// baseline (2566.381 us; speedup 1.0000x reference)
//
#include <hip/hip_runtime.h>
#include <math.h>

// Problem constants (from reference): B=8 H=16 S=1024 D=128, fp32.
#define NB 8
#define NH 16
#define NS 1024
#define ND 128
#define TQ 16   // q rows per block (4 per wave)
#define TK 64   // k cols per tile (lane = k)
#define PITCH 129  // +1 pad: LDS bank (l*129+d)%32 = (l+d)%32 -> 2-way = free

// LDS: qs 8KB + kv 33KB (shared K-then-V buffer) + ps 4KB = 45.3KB < 64KB
__launch_bounds__(256, 2)
__global__ void attn_fp32(const float* __restrict__ Q,
                          const float* __restrict__ K,
                          const float* __restrict__ V,
                          const float* __restrict__ scale,
                          float* __restrict__ out) {
  __shared__ float qs[TQ][ND];
  __shared__ float kv[TK][PITCH];
  __shared__ float ps[4][4][TK];

  const int tid = threadIdx.x;
  const int w = tid >> 6;   // wave id 0..3
  const int l = tid & 63;   // lane

  const int bid = blockIdx.x;
  const int qt = bid & 63;          // S/TQ = 64
  const int h  = (bid >> 6) & 15;
  const int b  = bid >> 10;

  const size_t bh = (size_t)b * NH + h;
  const float* Qb = Q + (bh * NS + (size_t)qt * TQ) * ND;
  const float* Kb = K + bh * NS * ND;
  const float* Vb = V + bh * NS * ND;

  // load q tile (2048 floats = 512 float4, 2 per thread), coalesced
  {
    const float4* Q4 = (const float4*)Qb;
    float4* qs4 = (float4*)&qs[0][0];
    qs4[tid] = Q4[tid];
    qs4[tid + 256] = Q4[tid + 256];
  }

  const int q0 = qt * TQ + w * 4;  // first global q row of this wave

  // scale row base pointers: scale[b,h,q,:] and scale[0,h,q,:]
  const float* sc0p[4];
  const float* sclp[4];
#pragma unroll
  for (int i = 0; i < 4; ++i) {
    const int qg = q0 + i;
    sc0p[i] = scale + ((size_t)h * NS + qg) * NS;      // batch-0 slice
    sclp[i] = scale + (bh * NS + qg) * NS;
  }

  float m[4]  = {-INFINITY, -INFINITY, -INFINITY, -INFINITY};
  float ls[4] = {0.f, 0.f, 0.f, 0.f};
  float oa[4] = {0.f, 0.f, 0.f, 0.f};  // out d = l
  float ob[4] = {0.f, 0.f, 0.f, 0.f};  // out d = 64+l

  for (int kt = 0; kt < NS / TK; ++kt) {
    __syncthreads();  // protect kv reuse from previous iteration's PV reads
    // ---- stage K tile into kv (scalar writes to honor pitch 129) ----
    {
      const float4* K4 = (const float4*)(Kb + (size_t)kt * TK * ND);
#pragma unroll
      for (int i = 0; i < 8; ++i) {
        const int f = tid + i * 256;
        const float4 t4 = K4[f];
        const int r = f >> 5, c = (f & 31) << 2;
        kv[r][c] = t4.x; kv[r][c + 1] = t4.y; kv[r][c + 2] = t4.z; kv[r][c + 3] = t4.w;
      }
    }
    __syncthreads();

    const int kg = kt * TK + l;
    // prefetch scale factors (coalesced: consecutive lanes -> consecutive k)
    float sc0[4], scl[4];
#pragma unroll
    for (int i = 0; i < 4; ++i) { sc0[i] = sc0p[i][kg]; scl[i] = sclp[i][kg]; }

    // ---- scores: lane l computes dot(q_i, K[kg]) for its 4 q rows ----
    float s[4] = {0.f, 0.f, 0.f, 0.f};
#pragma unroll 8
    for (int d = 0; d < ND; ++d) {
      const float kd = kv[l][d];              // (l+d)%32 banks: conflict-free
      s[0] = fmaf(qs[w * 4 + 0][d], kd, s[0]);  // broadcast reads
      s[1] = fmaf(qs[w * 4 + 1][d], kd, s[1]);
      s[2] = fmaf(qs[w * 4 + 2][d], kd, s[2]);
      s[3] = fmaf(qs[w * 4 + 3][d], kd, s[3]);
    }

    // ---- online softmax across the 64 k's of this tile ----
#pragma unroll
    for (int i = 0; i < 4; ++i) {
      const float sv = s[i] * scl[i] * rsqrtf(sc0[i]);  // s/sqrt(scale0)*scale
      float mx = sv;
#pragma unroll
      for (int off = 32; off > 0; off >>= 1) mx = fmaxf(mx, __shfl_xor(mx, off));
      const float mn = fmaxf(m[i], mx);
      const float p  = __expf(sv - mn);
      const float al = __expf(m[i] - mn);   // exp(-inf)=0 on first tile
      float psum = p;
#pragma unroll
      for (int off = 32; off > 0; off >>= 1) psum += __shfl_xor(psum, off);
      ls[i] = ls[i] * al + psum;
      m[i]  = mn;
      oa[i] *= al;
      ob[i] *= al;
      ps[w][i][l] = p;
    }

    __syncthreads();
    // ---- stage V tile into kv (same buffer; barriers order K-use -> V) ----
    {
      const float4* V4 = (const float4*)(Vb + (size_t)kt * TK * ND);
#pragma unroll
      for (int i = 0; i < 8; ++i) {
        const int f = tid + i * 256;
        const float4 t4 = V4[f];
        const int r = f >> 5, c = (f & 31) << 2;
        kv[r][c] = t4.x; kv[r][c + 1] = t4.y; kv[r][c + 2] = t4.z; kv[r][c + 3] = t4.w;
      }
    }
    __syncthreads();

    // ---- PV: lane l owns out dims d=l and d=64+l ----
#pragma unroll 4
    for (int k2 = 0; k2 < TK; ++k2) {
      const float v0 = kv[k2][l];
      const float v1 = kv[k2][64 + l];
#pragma unroll
      for (int i = 0; i < 4; ++i) {
        const float p = ps[w][i][k2];  // broadcast
        oa[i] = fmaf(p, v0, oa[i]);
        ob[i] = fmaf(p, v1, ob[i]);
      }
    }
  }

  // ---- epilogue: normalize and store ----
  float* op = out + (bh * NS + q0) * ND;
#pragma unroll
  for (int i = 0; i < 4; ++i) {
    const float inv = 1.0f / ls[i];
    op[(size_t)i * ND + l]      = oa[i] * inv;
    op[(size_t)i * ND + 64 + l] = ob[i] * inv;
  }
}

extern "C" void kernel_launch(void* const* d_in, const int* in_sizes, int n_in,
                              void* d_out, int out_size, void* d_ws, size_t ws_size,
                              hipStream_t stream) {
  const float* Q     = (const float*)d_in[0];
  const float* K     = (const float*)d_in[1];
  const float* V     = (const float*)d_in[2];
  const float* scale = (const float*)d_in[3];
  float* out = (float*)d_out;

  dim3 grid(NB * NH * (NS / TQ));  // 8192 blocks
  attn_fp32<<<grid, dim3(256), 0, stream>>>(Q, K, V, scale, out);
}

// Round 2
// 1803.624 us; speedup vs baseline: 1.4229x; 1.4229x over previous
//
#include <hip/hip_runtime.h>
#include <math.h>

#define NB 8
#define NH 16
#define NS 1024
#define ND 128

typedef float  f32x4 __attribute__((ext_vector_type(4)));
typedef short  s16x8 __attribute__((ext_vector_type(8)));
typedef short  s16x4 __attribute__((ext_vector_type(4)));

__device__ __forceinline__ short f2bf(float x) {
  return __builtin_bit_cast(short, (__bf16)x);
}
__device__ __forceinline__ float bf2f(short s) {
  return (float)__builtin_bit_cast(__bf16, s);
}

#define MFMA16(a, b, c) __builtin_amdgcn_mfma_f32_16x16x32_bf16(a, b, c, 0, 0, 0)

// ---------------- pre-pass: V [B,H,S,D] fp32 -> Vt [B,H,D,S] bf16 ----------------
__global__ void transpose_v(const float* __restrict__ V, short* __restrict__ Vt) {
  __shared__ short t[64 * 66];  // pitch 66: conflict-light both directions
  const int tid = threadIdx.x;
  const int dt = blockIdx.x, st = blockIdx.y, bh = blockIdx.z;
  const float* Vb = V + ((size_t)bh * NS + (size_t)st * 64) * ND + dt * 64;
#pragma unroll
  for (int i = 0; i < 4; ++i) {
    int f = tid + i * 256;          // 0..1023
    int s = f >> 4, c16 = f & 15;
    float4 v = *(const float4*)(Vb + (size_t)s * ND + c16 * 4);
    int base = s * 66 + c16 * 4;
    t[base + 0] = f2bf(v.x); t[base + 1] = f2bf(v.y);
    t[base + 2] = f2bf(v.z); t[base + 3] = f2bf(v.w);
  }
  __syncthreads();
  short* Ob = Vt + ((size_t)bh * ND + (size_t)dt * 64) * NS + (size_t)st * 64;
#pragma unroll
  for (int i = 0; i < 4; ++i) {
    int u = tid + i * 256;
    int d = u >> 4, sc = u & 15;
    s16x4 o;
    o[0] = t[(sc * 4 + 0) * 66 + d];
    o[1] = t[(sc * 4 + 1) * 66 + d];
    o[2] = t[(sc * 4 + 2) * 66 + d];
    o[3] = t[(sc * 4 + 3) * 66 + d];
    *(s16x4*)(Ob + (size_t)d * NS + sc * 4) = o;
  }
}

// ---------------- main MFMA flash-attention kernel ----------------
// block = 256 thr = 4 waves; BM=128 q rows (32/wave, 2 M-frags), BN=64 keys/tile.
// LDS tiles XOR-swizzled in 16B chunks (chunk' = chunk ^ (row & mask)) ->
// bank-uniform ds_read_b128 / staging writes, no padding. Total LDS = 64 KiB.
__launch_bounds__(256, 2)
__global__ void attn_mfma(const float* __restrict__ Q, const float* __restrict__ K,
                          const float* __restrict__ scale, const short* __restrict__ Vt,
                          float* __restrict__ out) {
  __shared__ short Kh[64 * 128];   // [key][d] bf16-hi, chunk^ (key&15)
  __shared__ short Kl[64 * 128];   // bf16-lo
  __shared__ short Vts[128 * 64];  // [d][key] bf16, chunk ^ (d&7)
  __shared__ short Ps[128 * 64];   // [q][key] bf16, chunk ^ (q&7); per-wave region

  const int tid = threadIdx.x;
  const int w = tid >> 6, l = tid & 63;
  const int quad = l >> 4, c = l & 15;

  const int bid = blockIdx.x;
  const int qblk = bid & 7;
  const int h = (bid >> 3) & 15;
  const int b = bid >> 7;
  const size_t bh = (size_t)b * NH + h;
  const int q0 = qblk * 128 + w * 32;  // wave's first global q row

  // ---- Q A-frags, fp32 global -> hi/lo bf16 registers (held全 kernel) ----
  s16x8 qhv[2][4], qlv[2][4];
  {
    const float* Qb = Q + (bh * NS + (size_t)q0) * ND;
#pragma unroll
    for (int mf = 0; mf < 2; ++mf)
#pragma unroll
      for (int kb = 0; kb < 4; ++kb) {
        const float* p = Qb + (size_t)(mf * 16 + c) * ND + kb * 32 + quad * 8;
        float x[8];
        *(float4*)&x[0] = *(const float4*)p;
        *(float4*)&x[4] = *(const float4*)(p + 4);
#pragma unroll
        for (int j = 0; j < 8; ++j) {
          short hi = f2bf(x[j]);
          qhv[mf][kb][j] = hi;
          qlv[mf][kb][j] = f2bf(x[j] - bf2f(hi));
        }
      }
  }

  float m_[2][4], ls[2][4];
  f32x4 O[2][8];
#pragma unroll
  for (int mf = 0; mf < 2; ++mf)
#pragma unroll
    for (int r = 0; r < 4; ++r) { m_[mf][r] = -INFINITY; ls[mf][r] = 0.f; }
#pragma unroll
  for (int mf = 0; mf < 2; ++mf)
#pragma unroll
    for (int n0 = 0; n0 < 8; ++n0) O[mf][n0] = (f32x4){0.f, 0.f, 0.f, 0.f};

  const float* sclb = scale + bh * (size_t)NS * NS;        // [row][col]
  const float* sc0b = scale + (size_t)h * NS * NS;         // batch-0 slice
  const short* Vg = Vt + bh * (size_t)ND * NS;

#pragma unroll 1
  for (int kt = 0; kt < NS / 64; ++kt) {
    __syncthreads();  // protect LDS reuse from previous tile's reads

    // ---- stage K tile: fp32 -> hi/lo bf16, swizzled ----
    {
      const float* Kt = K + (bh * NS + (size_t)kt * 64) * ND;
#pragma unroll
      for (int i = 0; i < 8; ++i) {
        int f = tid + i * 256;                 // 0..2047 float4s
        int key = f >> 5, d4 = (f & 31) << 2;  // d0
        float4 v = *(const float4*)(Kt + (size_t)key * ND + d4);
        short h0 = f2bf(v.x), h1 = f2bf(v.y), h2 = f2bf(v.z), h3 = f2bf(v.w);
        s16x4 hv = {h0, h1, h2, h3};
        s16x4 lv = {f2bf(v.x - bf2f(h0)), f2bf(v.y - bf2f(h1)),
                    f2bf(v.z - bf2f(h2)), f2bf(v.w - bf2f(h3))};
        int g = d4 >> 3;                 // 16B chunk 0..15
        int gp = g ^ (key & 15);
        int off = key * 128 + gp * 8 + (d4 & 7);
        *(s16x4*)&Kh[off] = hv;
        *(s16x4*)&Kl[off] = lv;
      }
      // ---- stage Vt tile (bf16 global, already transposed) ----
#pragma unroll
      for (int i = 0; i < 4; ++i) {
        int u = tid + i * 256;           // 0..1023 chunks
        int d = u >> 3, g = u & 7;
        s16x8 vv = *(const s16x8*)(Vg + (size_t)d * NS + kt * 64 + g * 8);
        int gp = g ^ (d & 7);
        *(s16x8*)&Vts[d * 64 + gp * 8] = vv;
      }
    }
    __syncthreads();

    // ---- scale prefetch for M-frag 0 (issued before MFMAs to hide latency) ----
    float scl0[16], sc00[16];
#pragma unroll
    for (int r = 0; r < 4; ++r)
#pragma unroll
      for (int n0 = 0; n0 < 4; ++n0) {
        size_t row = (size_t)(q0 + quad * 4 + r);
        size_t col = (size_t)(kt * 64 + n0 * 16 + c);
        scl0[r * 4 + n0] = sclb[row * NS + col];
        sc00[r * 4 + n0] = sc0b[row * NS + col];
      }

    // ---- QK^T: 3-MFMA hi/lo split, B-frags shared across both M-frags ----
    f32x4 S[2][4];
#pragma unroll
    for (int mf = 0; mf < 2; ++mf)
#pragma unroll
      for (int n0 = 0; n0 < 4; ++n0) S[mf][n0] = (f32x4){0.f, 0.f, 0.f, 0.f};
#pragma unroll
    for (int n0 = 0; n0 < 4; ++n0) {
#pragma unroll
      for (int kb = 0; kb < 4; ++kb) {
        int gp = ((kb << 2) + quad) ^ c;
        int off = (n0 * 16 + c) * 128 + gp * 8;
        const s16x8 bhf = *(const s16x8*)&Kh[off];
        const s16x8 blf = *(const s16x8*)&Kl[off];
        S[0][n0] = MFMA16(qhv[0][kb], bhf, S[0][n0]);
        S[0][n0] = MFMA16(qhv[0][kb], blf, S[0][n0]);
        S[0][n0] = MFMA16(qlv[0][kb], bhf, S[0][n0]);
        S[1][n0] = MFMA16(qhv[1][kb], bhf, S[1][n0]);
        S[1][n0] = MFMA16(qhv[1][kb], blf, S[1][n0]);
        S[1][n0] = MFMA16(qlv[1][kb], bhf, S[1][n0]);
      }
    }

    // ---- online softmax + P write (bf16, swizzled). Per-wave rows only:
    //      no barrier needed between P write and P read. ----
#define SOFTMAX_MF(MF, SCL, SC0)                                               \
    {                                                                          \
      const int prow_base = w * 32 + (MF) * 16;                                \
      _Pragma("unroll")                                                        \
      for (int r = 0; r < 4; ++r) {                                            \
        float sv[4];                                                           \
        _Pragma("unroll")                                                      \
        for (int n0 = 0; n0 < 4; ++n0)                                         \
          sv[n0] = S[MF][n0][r] * (SCL)[r * 4 + n0] * rsqrtf((SC0)[r * 4 + n0]); \
        float mx = fmaxf(fmaxf(sv[0], sv[1]), fmaxf(sv[2], sv[3]));            \
        _Pragma("unroll")                                                      \
        for (int off_ = 8; off_ > 0; off_ >>= 1) mx = fmaxf(mx, __shfl_xor(mx, off_)); \
        float mn = fmaxf(m_[MF][r], mx);                                       \
        float al = __expf(m_[MF][r] - mn);                                     \
        float ps = 0.f;                                                        \
        short pb[4];                                                           \
        _Pragma("unroll")                                                      \
        for (int n0 = 0; n0 < 4; ++n0) {                                       \
          float p = __expf(sv[n0] - mn);                                       \
          ps += p;                                                             \
          pb[n0] = f2bf(p);                                                    \
        }                                                                      \
        _Pragma("unroll")                                                      \
        for (int off_ = 8; off_ > 0; off_ >>= 1) ps += __shfl_xor(ps, off_);   \
        ls[MF][r] = ls[MF][r] * al + ps;                                       \
        m_[MF][r] = mn;                                                        \
        _Pragma("unroll")                                                      \
        for (int n0 = 0; n0 < 8; ++n0) O[MF][n0][r] *= al;                     \
        const int row = prow_base + quad * 4 + r;                              \
        _Pragma("unroll")                                                      \
        for (int n0 = 0; n0 < 4; ++n0) {                                       \
          int chunk = 2 * n0 + (c >> 3);                                       \
          int gp = chunk ^ (row & 7);                                          \
          Ps[row * 64 + gp * 8 + (c & 7)] = pb[n0];                            \
        }                                                                      \
      }                                                                        \
    }

    SOFTMAX_MF(0, scl0, sc00)

    float scl1[16], sc01[16];
#pragma unroll
    for (int r = 0; r < 4; ++r)
#pragma unroll
      for (int n0 = 0; n0 < 4; ++n0) {
        size_t row = (size_t)(q0 + 16 + quad * 4 + r);
        size_t col = (size_t)(kt * 64 + n0 * 16 + c);
        scl1[r * 4 + n0] = sclb[row * NS + col];
        sc01[r * 4 + n0] = sc0b[row * NS + col];
      }
    SOFTMAX_MF(1, scl1, sc01)

    // ---- PV: O += P * V ----
    s16x8 pf[2][2];
#pragma unroll
    for (int mf = 0; mf < 2; ++mf)
#pragma unroll
      for (int kb = 0; kb < 2; ++kb) {
        int row = w * 32 + mf * 16 + c;
        int gp = (kb * 4 + quad) ^ (c & 7);
        pf[mf][kb] = *(const s16x8*)&Ps[row * 64 + gp * 8];
      }
#pragma unroll
    for (int n0 = 0; n0 < 8; ++n0) {
#pragma unroll
      for (int kb = 0; kb < 2; ++kb) {
        int gp = (kb * 4 + quad) ^ (c & 7);
        const s16x8 vf = *(const s16x8*)&Vts[(n0 * 16 + c) * 64 + gp * 8];
        O[0][n0] = MFMA16(pf[0][kb], vf, O[0][n0]);
        O[1][n0] = MFMA16(pf[1][kb], vf, O[1][n0]);
      }
    }
  }  // kt

  // ---- epilogue: normalize + store (C-layout: row=quad*4+r, col=n0*16+c) ----
  float* ob = out + (bh * NS + (size_t)q0) * ND;
#pragma unroll
  for (int mf = 0; mf < 2; ++mf)
#pragma unroll
    for (int r = 0; r < 4; ++r) {
      float inv = 1.0f / ls[mf][r];
      int row = mf * 16 + quad * 4 + r;
#pragma unroll
      for (int n0 = 0; n0 < 8; ++n0)
        ob[(size_t)row * ND + n0 * 16 + c] = O[mf][n0][r] * inv;
    }
}

// ---------------- fallback (R1 fp32 kernel) if ws too small ----------------
#define TQ 16
#define TK 64
#define PITCH 129
__launch_bounds__(256, 2)
__global__ void attn_fp32(const float* __restrict__ Q, const float* __restrict__ K,
                          const float* __restrict__ V, const float* __restrict__ scale,
                          float* __restrict__ out) {
  __shared__ float qs[TQ][ND];
  __shared__ float kv[TK][PITCH];
  __shared__ float ps[4][4][TK];
  const int tid = threadIdx.x;
  const int w = tid >> 6, l = tid & 63;
  const int bid = blockIdx.x;
  const int qt = bid & 63, h = (bid >> 6) & 15, b = bid >> 10;
  const size_t bh = (size_t)b * NH + h;
  const float* Qb = Q + (bh * NS + (size_t)qt * TQ) * ND;
  const float* Kb = K + bh * NS * ND;
  const float* Vb = V + bh * NS * ND;
  {
    const float4* Q4 = (const float4*)Qb;
    float4* qs4 = (float4*)&qs[0][0];
    qs4[tid] = Q4[tid];
    qs4[tid + 256] = Q4[tid + 256];
  }
  const int q0 = qt * TQ + w * 4;
  const float* sc0p[4];
  const float* sclp[4];
#pragma unroll
  for (int i = 0; i < 4; ++i) {
    const int qg = q0 + i;
    sc0p[i] = scale + ((size_t)h * NS + qg) * NS;
    sclp[i] = scale + (bh * NS + qg) * NS;
  }
  float m[4] = {-INFINITY, -INFINITY, -INFINITY, -INFINITY};
  float lsum[4] = {0.f, 0.f, 0.f, 0.f};
  float oa[4] = {0.f, 0.f, 0.f, 0.f};
  float ob[4] = {0.f, 0.f, 0.f, 0.f};
  for (int kt = 0; kt < NS / TK; ++kt) {
    __syncthreads();
    {
      const float4* K4 = (const float4*)(Kb + (size_t)kt * TK * ND);
#pragma unroll
      for (int i = 0; i < 8; ++i) {
        const int f = tid + i * 256;
        const float4 t4 = K4[f];
        const int r = f >> 5, cc = (f & 31) << 2;
        kv[r][cc] = t4.x; kv[r][cc + 1] = t4.y; kv[r][cc + 2] = t4.z; kv[r][cc + 3] = t4.w;
      }
    }
    __syncthreads();
    const int kg = kt * TK + l;
    float sc0[4], scl[4];
#pragma unroll
    for (int i = 0; i < 4; ++i) { sc0[i] = sc0p[i][kg]; scl[i] = sclp[i][kg]; }
    float s[4] = {0.f, 0.f, 0.f, 0.f};
#pragma unroll 8
    for (int d = 0; d < ND; ++d) {
      const float kd = kv[l][d];
      s[0] = fmaf(qs[w * 4 + 0][d], kd, s[0]);
      s[1] = fmaf(qs[w * 4 + 1][d], kd, s[1]);
      s[2] = fmaf(qs[w * 4 + 2][d], kd, s[2]);
      s[3] = fmaf(qs[w * 4 + 3][d], kd, s[3]);
    }
#pragma unroll
    for (int i = 0; i < 4; ++i) {
      const float sv = s[i] * scl[i] * rsqrtf(sc0[i]);
      float mx = sv;
#pragma unroll
      for (int off = 32; off > 0; off >>= 1) mx = fmaxf(mx, __shfl_xor(mx, off));
      const float mn = fmaxf(m[i], mx);
      const float p = __expf(sv - mn);
      const float al = __expf(m[i] - mn);
      float psum = p;
#pragma unroll
      for (int off = 32; off > 0; off >>= 1) psum += __shfl_xor(psum, off);
      lsum[i] = lsum[i] * al + psum;
      m[i] = mn;
      oa[i] *= al;
      ob[i] *= al;
      ps[w][i][l] = p;
    }
    __syncthreads();
    {
      const float4* V4 = (const float4*)(Vb + (size_t)kt * TK * ND);
#pragma unroll
      for (int i = 0; i < 8; ++i) {
        const int f = tid + i * 256;
        const float4 t4 = V4[f];
        const int r = f >> 5, cc = (f & 31) << 2;
        kv[r][cc] = t4.x; kv[r][cc + 1] = t4.y; kv[r][cc + 2] = t4.z; kv[r][cc + 3] = t4.w;
      }
    }
    __syncthreads();
#pragma unroll 4
    for (int k2 = 0; k2 < TK; ++k2) {
      const float v0 = kv[k2][l];
      const float v1 = kv[k2][64 + l];
#pragma unroll
      for (int i = 0; i < 4; ++i) {
        const float p = ps[w][i][k2];
        oa[i] = fmaf(p, v0, oa[i]);
        ob[i] = fmaf(p, v1, ob[i]);
      }
    }
  }
  float* op = out + (bh * NS + q0) * ND;
#pragma unroll
  for (int i = 0; i < 4; ++i) {
    const float inv = 1.0f / lsum[i];
    op[(size_t)i * ND + l] = oa[i] * inv;
    op[(size_t)i * ND + 64 + l] = ob[i] * inv;
  }
}

extern "C" void kernel_launch(void* const* d_in, const int* in_sizes, int n_in,
                              void* d_out, int out_size, void* d_ws, size_t ws_size,
                              hipStream_t stream) {
  const float* Q = (const float*)d_in[0];
  const float* K = (const float*)d_in[1];
  const float* V = (const float*)d_in[2];
  const float* scale = (const float*)d_in[3];
  float* out = (float*)d_out;

  const size_t vt_bytes = (size_t)NB * NH * ND * NS * sizeof(short);  // 32 MiB
  if (ws_size >= vt_bytes) {
    short* Vt = (short*)d_ws;
    transpose_v<<<dim3(ND / 64, NS / 64, NB * NH), dim3(256), 0, stream>>>(V, Vt);
    attn_mfma<<<dim3(NB * NH * (NS / 128)), dim3(256), 0, stream>>>(Q, K, scale, Vt, out);
  } else {
    attn_fp32<<<dim3(NB * NH * (NS / TQ)), dim3(256), 0, stream>>>(Q, K, V, scale, out);
  }
}

// Round 3
// 1073.596 us; speedup vs baseline: 2.3905x; 1.6800x over previous
//
#include <hip/hip_runtime.h>
#include <math.h>

#define NB 8
#define NH 16
#define NS 1024
#define ND 128

typedef float    f32x4 __attribute__((ext_vector_type(4)));
typedef _Float16 f16x8 __attribute__((ext_vector_type(8)));
typedef _Float16 f16x4 __attribute__((ext_vector_type(4)));
typedef short    s16x4 __attribute__((ext_vector_type(4)));
typedef short    s16x8 __attribute__((ext_vector_type(8)));

#define MFMAH(a, b, c) __builtin_amdgcn_mfma_f32_16x16x32_f16(a, b, c, 0, 0, 0)

// async 16B global->LDS (wave-uniform base + lane*16 — layouts are pre-swizzled
// in the global "image" buffers so the contiguous landing IS the swizzled tile)
__device__ __forceinline__ void gload16(const void* g, void* l) {
  __builtin_amdgcn_global_load_lds(
      (const __attribute__((address_space(1))) void*)g,
      (__attribute__((address_space(3))) void*)l, 16, 0, 0);
}

// ---------------- pre-pass 1: E = scale * rsqrt(scale[0]) -> fp16 ----------------
// [B,H,S,S] fp32 (512 MiB) -> fp16 (256 MiB). scale0 read once per block.
__global__ void prep_e(const float* __restrict__ scale, _Float16* __restrict__ E) {
  const size_t i0 = ((size_t)blockIdx.x * 256 + threadIdx.x) * 8;  // within H*S*S = 2^24
  float4 a0 = *(const float4*)(scale + i0);
  float4 b0 = *(const float4*)(scale + i0 + 4);
  float r[8] = {rsqrtf(a0.x), rsqrtf(a0.y), rsqrtf(a0.z), rsqrtf(a0.w),
                rsqrtf(b0.x), rsqrtf(b0.y), rsqrtf(b0.z), rsqrtf(b0.w)};
#pragma unroll
  for (int b = 0; b < NB; ++b) {
    const float* sp = scale + ((size_t)b << 24) + i0;
    float4 a = *(const float4*)sp;
    float4 bb = *(const float4*)(sp + 4);
    f16x8 o = {(_Float16)(a.x * r[0]), (_Float16)(a.y * r[1]),
               (_Float16)(a.z * r[2]), (_Float16)(a.w * r[3]),
               (_Float16)(bb.x * r[4]), (_Float16)(bb.y * r[5]),
               (_Float16)(bb.z * r[6]), (_Float16)(bb.w * r[7])};
    *(f16x8*)(E + ((size_t)b << 24) + i0) = o;
  }
}

// ---------------- pre-pass 2: K fp32 -> fp16 LDS-image (per (bh,kt): 64key x 128d,
// 16B chunks swizzled g^=key&15) ----------------
__global__ void prep_k(const float* __restrict__ K, short* __restrict__ Kimg) {
  const int kt = blockIdx.x & 15, bh = blockIdx.x >> 4;
  const float* Kt = K + ((size_t)bh * NS + kt * 64) * ND;
  short* img = Kimg + ((size_t)bh * 16 + kt) * 8192;
#pragma unroll
  for (int i = 0; i < 8; ++i) {
    int f = threadIdx.x + i * 256;          // 0..2047 float4
    int key = f >> 5, d4 = (f & 31) << 2;
    float4 v = *(const float4*)(Kt + (size_t)key * ND + d4);
    f16x4 hv = {(_Float16)v.x, (_Float16)v.y, (_Float16)v.z, (_Float16)v.w};
    int gp = (d4 >> 3) ^ (key & 15);
    *(f16x4*)(img + key * 128 + gp * 8 + (d4 & 7)) = hv;
  }
}

// ---------------- pre-pass 3: V fp32 -> V^T fp16 LDS-image (per (bh,kt):
// 128d x 64key, 16B chunks swizzled g^=d&7) ----------------
__global__ void prep_v(const float* __restrict__ V, short* __restrict__ Vimg) {
  __shared__ _Float16 t[64 * 132];  // [key][d], pad->8B-aligned rows
  const int kt = blockIdx.x & 15, bh = blockIdx.x >> 4;
  const float* Vt = V + ((size_t)bh * NS + kt * 64) * ND;
#pragma unroll
  for (int i = 0; i < 8; ++i) {
    int f = threadIdx.x + i * 256;
    int key = f >> 5, d4 = (f & 31) << 2;
    float4 v = *(const float4*)(Vt + (size_t)key * ND + d4);
    *(f16x4*)&t[key * 132 + d4] =
        (f16x4){(_Float16)v.x, (_Float16)v.y, (_Float16)v.z, (_Float16)v.w};
  }
  __syncthreads();
  short* img = Vimg + ((size_t)bh * 16 + kt) * 8192;
#pragma unroll
  for (int i = 0; i < 4; ++i) {
    int u = threadIdx.x + i * 256;  // 0..1023
    int d = u >> 3, g = u & 7;
    f16x8 o;
#pragma unroll
    for (int e = 0; e < 8; ++e) o[e] = t[(g * 8 + e) * 132 + d];
    *(f16x8*)(img + d * 64 + ((g ^ (d & 7)) * 8)) = o;
  }
}

// ---------------- main fp16 MFMA flash-attention ----------------
// 256 thr = 4 waves; BM=128 (32 q/wave), BN=64 keys/tile.
// QK^T computed transposed (A=K, B=Q -> S^T[key][q]) so E/scale reads vectorize.
// LDS 50 KiB -> 3 blocks/CU.
template <bool USE_E>
__launch_bounds__(256, 3)
__global__ void attn_f16(const float* __restrict__ Q, const short* __restrict__ Kimg,
                         const short* __restrict__ Vimg, const _Float16* __restrict__ E,
                         const float* __restrict__ scale, float* __restrict__ out) {
  __shared__ short Ks[64 * 128];        // 16 KiB  [key][d] swizzled
  __shared__ short Vs[128 * 64];        // 16 KiB  [d][key] swizzled
  __shared__ _Float16 Ps[128 * 72];     // 18 KiB  [q][key] stride 72 (16B-aligned rows)

  const int tid = threadIdx.x;
  const int w = tid >> 6, l = tid & 63;
  const int quad = l >> 4, c = l & 15;

  // XCD swizzle: all 8 q-blocks of one (b,h) -> same XCD (id%8 = bh&7),
  // dispatched consecutively (qblk fast) -> K/V tiles L2-hit.
  const int x = blockIdx.x;
  const int bh = ((x >> 6) << 3) | (x & 7);
  const int qblk = (x >> 3) & 7;
  const int q0 = qblk * 128 + w * 32;   // wave's first global q row

  // Q B-fragments fp32->fp16: B[n=q][k=d], lane holds Q[q0+nf*16+c][kb*32+quad*8+j]
  f16x8 qf[2][4];
  {
    const float* Qb = Q + ((size_t)bh * NS + q0) * ND;
#pragma unroll
    for (int nf = 0; nf < 2; ++nf)
#pragma unroll
      for (int kb = 0; kb < 4; ++kb) {
        const float* p = Qb + (size_t)(nf * 16 + c) * ND + kb * 32 + quad * 8;
        float4 a = *(const float4*)p;
        float4 b = *(const float4*)(p + 4);
        qf[nf][kb] = (f16x8){(_Float16)a.x, (_Float16)a.y, (_Float16)a.z, (_Float16)a.w,
                             (_Float16)b.x, (_Float16)b.y, (_Float16)b.z, (_Float16)b.w};
      }
  }

  float m_[2] = {-INFINITY, -INFINITY}, ls_[2] = {0.f, 0.f};
  f32x4 O[2][8];
#pragma unroll
  for (int pf = 0; pf < 2; ++pf)
#pragma unroll
    for (int n0 = 0; n0 < 8; ++n0) O[pf][n0] = (f32x4){0.f, 0.f, 0.f, 0.f};

  const short* Kb = Kimg + (size_t)bh * (16 * 8192);
  const short* Vb = Vimg + (size_t)bh * (16 * 8192);
  const _Float16* Eb = E + ((size_t)bh << 20);
  const float* sclb = scale + ((size_t)bh << 20);
  const float* sc0b = scale + ((size_t)(bh & 15) << 20);

#pragma unroll 1
  for (int kt = 0; kt < 16; ++kt) {
    __syncthreads();  // previous tile's LDS reads done
    {
      const short* kg = Kb + kt * 8192 + tid * 8;
      const short* vg = Vb + kt * 8192 + tid * 8;
#pragma unroll
      for (int i = 0; i < 4; ++i) {
        gload16(kg + i * 2048, &Ks[tid * 8 + i * 2048]);
        gload16(vg + i * 2048, &Vs[tid * 8 + i * 2048]);
      }
    }
    // scale operand loads (vectorized thanks to transposed S layout); drain with barrier
    f16x4 ef[2][4];
    f32x4 sclv[2][4], sc0v[2][4];
    if (USE_E) {
#pragma unroll
      for (int nf = 0; nf < 2; ++nf)
#pragma unroll
        for (int m0 = 0; m0 < 4; ++m0)
          ef[nf][m0] = *(const f16x4*)(Eb + (size_t)(q0 + nf * 16 + c) * NS +
                                       kt * 64 + m0 * 16 + quad * 4);
    } else {
#pragma unroll
      for (int nf = 0; nf < 2; ++nf)
#pragma unroll
        for (int m0 = 0; m0 < 4; ++m0) {
          size_t off = (size_t)(q0 + nf * 16 + c) * NS + kt * 64 + m0 * 16 + quad * 4;
          sclv[nf][m0] = *(const f32x4*)(sclb + off);
          sc0v[nf][m0] = *(const f32x4*)(sc0b + off);
        }
    }
    __syncthreads();  // K/V tiles landed

    // ---- S^T = K * Q^T : D[m=key][n=q] ----
    f32x4 S[2][4];
#pragma unroll
    for (int nf = 0; nf < 2; ++nf)
#pragma unroll
      for (int m0 = 0; m0 < 4; ++m0) S[nf][m0] = (f32x4){0.f, 0.f, 0.f, 0.f};
#pragma unroll
    for (int m0 = 0; m0 < 4; ++m0) {
#pragma unroll
      for (int kb = 0; kb < 4; ++kb) {
        const f16x8 a = *(const f16x8*)&Ks[(m0 * 16 + c) * 128 + ((((kb << 2) | quad)) ^ c) * 8];
        S[0][m0] = MFMAH(a, qf[0][kb], S[0][m0]);
        S[1][m0] = MFMAH(a, qf[1][kb], S[1][m0]);
      }
    }

    // ---- online softmax (row = q at lane c; keys spread over m0,quad,reg) ----
    float al2[2];
#pragma unroll
    for (int nf = 0; nf < 2; ++nf) {
      float sv[16];
#pragma unroll
      for (int m0 = 0; m0 < 4; ++m0)
#pragma unroll
        for (int r = 0; r < 4; ++r) {
          float e = USE_E ? (float)ef[nf][m0][r]
                          : sclv[nf][m0][r] * rsqrtf(sc0v[nf][m0][r]);
          sv[m0 * 4 + r] = S[nf][m0][r] * e;
        }
      float tm = sv[0];
#pragma unroll
      for (int i = 1; i < 16; ++i) tm = fmaxf(tm, sv[i]);
      tm = fmaxf(tm, __shfl_xor(tm, 16));
      tm = fmaxf(tm, __shfl_xor(tm, 32));
      float mn = fmaxf(m_[nf], tm);
      float al = __expf(m_[nf] - mn);
      float ps = 0.f;
      _Float16 pb[16];
#pragma unroll
      for (int i = 0; i < 16; ++i) {
        float p = __expf(sv[i] - mn);
        ps += p;
        pb[i] = (_Float16)p;
      }
      ps += __shfl_xor(ps, 16);
      ps += __shfl_xor(ps, 32);
      ls_[nf] = ls_[nf] * al + ps;
      m_[nf] = mn;
      al2[nf] = al;
      // write P^T fragment -> Ps[q][key] (per-wave rows; no barrier needed)
      _Float16* pr = &Ps[(size_t)(w * 32 + nf * 16 + c) * 72];
#pragma unroll
      for (int m0 = 0; m0 < 4; ++m0)
        *(f16x4*)(pr + m0 * 16 + quad * 4) =
            (f16x4){pb[m0 * 4], pb[m0 * 4 + 1], pb[m0 * 4 + 2], pb[m0 * 4 + 3]};
    }

    // ---- rescale O by alpha (alpha lives at lane c=q%16 -> broadcast) ----
#pragma unroll
    for (int pf = 0; pf < 2; ++pf) {
      float ar[4];
#pragma unroll
      for (int r = 0; r < 4; ++r) ar[r] = __shfl(al2[pf], quad * 4 + r);
#pragma unroll
      for (int n0 = 0; n0 < 8; ++n0)
#pragma unroll
        for (int r = 0; r < 4; ++r) O[pf][n0][r] *= ar[r];
    }

    // ---- PV: O[q][d] += P * V (A=P from Ps, B=V^T from Vs) ----
    f16x8 pfr[2][2];
#pragma unroll
    for (int pf = 0; pf < 2; ++pf)
#pragma unroll
      for (int kb = 0; kb < 2; ++kb)
        pfr[pf][kb] = *(const f16x8*)&Ps[(size_t)(w * 32 + pf * 16 + c) * 72 +
                                         kb * 32 + quad * 8];
#pragma unroll
    for (int n0 = 0; n0 < 8; ++n0) {
#pragma unroll
      for (int kb = 0; kb < 2; ++kb) {
        const f16x8 b =
            *(const f16x8*)&Vs[(n0 * 16 + c) * 64 + ((((kb << 2) | quad)) ^ (c & 7)) * 8];
        O[0][n0] = MFMAH(pfr[0][kb], b, O[0][n0]);
        O[1][n0] = MFMAH(pfr[1][kb], b, O[1][n0]);
      }
    }
  }  // kt

  // ---- epilogue ----
  float* ob = out + ((size_t)bh * NS + q0) * ND;
#pragma unroll
  for (int pf = 0; pf < 2; ++pf)
#pragma unroll
    for (int r = 0; r < 4; ++r) {
      float lv = __shfl(ls_[pf], quad * 4 + r);
      float inv = 1.0f / lv;
      int row = pf * 16 + quad * 4 + r;
#pragma unroll
      for (int n0 = 0; n0 < 8; ++n0)
        ob[(size_t)row * ND + n0 * 16 + c] = O[pf][n0][r] * inv;
    }
}

// ---------------- fallback (R1 fp32 kernel, verified) ----------------
#define TQ 16
#define TK 64
#define PITCH 129
__launch_bounds__(256, 2)
__global__ void attn_fp32(const float* __restrict__ Q, const float* __restrict__ K,
                          const float* __restrict__ V, const float* __restrict__ scale,
                          float* __restrict__ out) {
  __shared__ float qs[TQ][ND];
  __shared__ float kv[TK][PITCH];
  __shared__ float ps[4][4][TK];
  const int tid = threadIdx.x;
  const int w = tid >> 6, l = tid & 63;
  const int bid = blockIdx.x;
  const int qt = bid & 63, h = (bid >> 6) & 15, b = bid >> 10;
  const size_t bh = (size_t)b * NH + h;
  const float* Qb = Q + (bh * NS + (size_t)qt * TQ) * ND;
  const float* Kb = K + bh * NS * ND;
  const float* Vb = V + bh * NS * ND;
  {
    const float4* Q4 = (const float4*)Qb;
    float4* qs4 = (float4*)&qs[0][0];
    qs4[tid] = Q4[tid];
    qs4[tid + 256] = Q4[tid + 256];
  }
  const int q0 = qt * TQ + w * 4;
  const float* sc0p[4];
  const float* sclp[4];
#pragma unroll
  for (int i = 0; i < 4; ++i) {
    const int qg = q0 + i;
    sc0p[i] = scale + ((size_t)h * NS + qg) * NS;
    sclp[i] = scale + (bh * NS + qg) * NS;
  }
  float m[4] = {-INFINITY, -INFINITY, -INFINITY, -INFINITY};
  float lsum[4] = {0.f, 0.f, 0.f, 0.f};
  float oa[4] = {0.f, 0.f, 0.f, 0.f};
  float ob[4] = {0.f, 0.f, 0.f, 0.f};
  for (int kt = 0; kt < NS / TK; ++kt) {
    __syncthreads();
    {
      const float4* K4 = (const float4*)(Kb + (size_t)kt * TK * ND);
#pragma unroll
      for (int i = 0; i < 8; ++i) {
        const int f = tid + i * 256;
        const float4 t4 = K4[f];
        const int r = f >> 5, cc = (f & 31) << 2;
        kv[r][cc] = t4.x; kv[r][cc + 1] = t4.y; kv[r][cc + 2] = t4.z; kv[r][cc + 3] = t4.w;
      }
    }
    __syncthreads();
    const int kg = kt * TK + l;
    float sc0[4], scl[4];
#pragma unroll
    for (int i = 0; i < 4; ++i) { sc0[i] = sc0p[i][kg]; scl[i] = sclp[i][kg]; }
    float s[4] = {0.f, 0.f, 0.f, 0.f};
#pragma unroll 8
    for (int d = 0; d < ND; ++d) {
      const float kd = kv[l][d];
      s[0] = fmaf(qs[w * 4 + 0][d], kd, s[0]);
      s[1] = fmaf(qs[w * 4 + 1][d], kd, s[1]);
      s[2] = fmaf(qs[w * 4 + 2][d], kd, s[2]);
      s[3] = fmaf(qs[w * 4 + 3][d], kd, s[3]);
    }
#pragma unroll
    for (int i = 0; i < 4; ++i) {
      const float svv = s[i] * scl[i] * rsqrtf(sc0[i]);
      float mx = svv;
#pragma unroll
      for (int off = 32; off > 0; off >>= 1) mx = fmaxf(mx, __shfl_xor(mx, off));
      const float mn = fmaxf(m[i], mx);
      const float p = __expf(svv - mn);
      const float al = __expf(m[i] - mn);
      float psum = p;
#pragma unroll
      for (int off = 32; off > 0; off >>= 1) psum += __shfl_xor(psum, off);
      lsum[i] = lsum[i] * al + psum;
      m[i] = mn;
      oa[i] *= al;
      ob[i] *= al;
      ps[w][i][l] = p;
    }
    __syncthreads();
    {
      const float4* V4 = (const float4*)(Vb + (size_t)kt * TK * ND);
#pragma unroll
      for (int i = 0; i < 8; ++i) {
        const int f = tid + i * 256;
        const float4 t4 = V4[f];
        const int r = f >> 5, cc = (f & 31) << 2;
        kv[r][cc] = t4.x; kv[r][cc + 1] = t4.y; kv[r][cc + 2] = t4.z; kv[r][cc + 3] = t4.w;
      }
    }
    __syncthreads();
#pragma unroll 4
    for (int k2 = 0; k2 < TK; ++k2) {
      const float v0 = kv[k2][l];
      const float v1 = kv[k2][64 + l];
#pragma unroll
      for (int i = 0; i < 4; ++i) {
        const float p = ps[w][i][k2];
        oa[i] = fmaf(p, v0, oa[i]);
        ob[i] = fmaf(p, v1, ob[i]);
      }
    }
  }
  float* op = out + (bh * NS + q0) * ND;
#pragma unroll
  for (int i = 0; i < 4; ++i) {
    const float inv = 1.0f / lsum[i];
    op[(size_t)i * ND + l] = oa[i] * inv;
    op[(size_t)i * ND + 64 + l] = ob[i] * inv;
  }
}

extern "C" void kernel_launch(void* const* d_in, const int* in_sizes, int n_in,
                              void* d_out, int out_size, void* d_ws, size_t ws_size,
                              hipStream_t stream) {
  const float* Q = (const float*)d_in[0];
  const float* K = (const float*)d_in[1];
  const float* V = (const float*)d_in[2];
  const float* scale = (const float*)d_in[3];
  float* out = (float*)d_out;

  const size_t KV_BYTES = (size_t)NB * NH * NS * ND * 2;        // 32 MiB each
  const size_t E_BYTES = (size_t)NB * NH * NS * NS * 2;         // 256 MiB
  const size_t needB = 2 * KV_BYTES;                            // 64 MiB
  const size_t needA = needB + E_BYTES;                         // 320 MiB

  if (ws_size >= needB) {
    short* Kimg = (short*)d_ws;
    short* Vimg = (short*)((char*)d_ws + KV_BYTES);
    prep_k<<<dim3(NB * NH * 16), dim3(256), 0, stream>>>(K, Kimg);
    prep_v<<<dim3(NB * NH * 16), dim3(256), 0, stream>>>(V, Vimg);
    if (ws_size >= needA) {
      _Float16* E = (_Float16*)((char*)d_ws + needB);
      prep_e<<<dim3(8192), dim3(256), 0, stream>>>(scale, E);
      attn_f16<true><<<dim3(1024), dim3(256), 0, stream>>>(Q, Kimg, Vimg, E, scale, out);
    } else {
      attn_f16<false><<<dim3(1024), dim3(256), 0, stream>>>(Q, Kimg, Vimg, nullptr, scale, out);
    }
  } else {
    attn_fp32<<<dim3(NB * NH * (NS / TK) * 4), dim3(256), 0, stream>>>(Q, K, V, scale, out);
  }
}